// Round 12
// baseline (746.534 us; speedup 1.0000x reference)
//
#include <hip/hip_runtime.h>
#include <hip/hip_bf16.h>

#define SDIM 38
#define RDIM 340
#define HC   128
#define SC   4
#define RC   3
#define NO   7
#define LCONV 4
#define BATCH 512
#define SR   378
#define NN   (BATCH*SR)     // 193536
#define NS   (BATCH*SDIM)   // 19456
#define NR   (BATCH*RDIM)   // 174080
#define EE   3072000
#define EPSV 1e-5f
#define NBUK 756            // NN/256 exactly
#define BCAP 4800           // bucket capacity; mean 4064, sigma 64
#define BK_BLOCKS 256
#define BK_EDGES  12000     // 256*12000 = 3,072,000 = EE
#define NSB 76              // ceil(NS/256)

// xb is stored panel-swizzled in MFMA A-fragment order:
//   panel p = node>>4, m = node&15; channel c -> ks=c>>5, q=(c>>3)&3, e=c&7
//   element addr = p*2048 + ks*512 + (q*16+m)*8 + e
// so gemm's A-load (lane = q*16+m) is a contiguous 1KB wave-load.

typedef short v8s __attribute__((ext_vector_type(8)));
typedef float v4f __attribute__((ext_vector_type(4)));
typedef float v2f __attribute__((ext_vector_type(2)));

__device__ __forceinline__ float leaky(float v){ return v > 0.f ? v : 0.2f*v; }

// round-to-nearest-even fp32 -> bf16 (as ushort)
__device__ __forceinline__ unsigned short f2bf(float f){
    union { float f; unsigned u; } v; v.f = f;
    unsigned r = v.u + 0x7fffu + ((v.u >> 16) & 1u);
    return (unsigned short)(r >> 16);
}
// unpack 4 bf16 (uint2) -> float4
__device__ __forceinline__ float4 bf4_to_f4(uint2 p){
    float4 r;
    r.x = __uint_as_float(p.x << 16);
    r.y = __uint_as_float(p.x & 0xffff0000u);
    r.z = __uint_as_float(p.y << 16);
    r.w = __uint_as_float(p.y & 0xffff0000u);
    return r;
}
// pack 4 fp32 -> 4 fp8 e4m3 bytes (HW convert)
__device__ __forceinline__ unsigned f4_to_fp8x4(float a, float b, float c, float d){
    int v = 0;
    v = __builtin_amdgcn_cvt_pk_fp8_f32(a, b, v, false);
    v = __builtin_amdgcn_cvt_pk_fp8_f32(c, d, v, true);
    return (unsigned)v;
}

// ---------------- batchnorm stats (fused s + r) ----------------
__global__ void stats_kernel(const float* __restrict__ s_x, const float* __restrict__ r_x,
                             float* __restrict__ stats){
    int tid = threadIdx.x;
    __shared__ float sh[256][8];
    if (blockIdx.x < NSB){
        int r = blockIdx.x*256 + tid;
        float4 v = make_float4(0.f,0.f,0.f,0.f);
        if (r < NS) v = *(const float4*)(s_x + (size_t)r*SC);
        sh[tid][0]=v.x; sh[tid][1]=v.y; sh[tid][2]=v.z; sh[tid][3]=v.w;
        sh[tid][4]=v.x*v.x; sh[tid][5]=v.y*v.y; sh[tid][6]=v.z*v.z; sh[tid][7]=v.w*v.w;
        __syncthreads();
        for (int s=128; s>0; s>>=1){
            if (tid < s){
                #pragma unroll
                for (int k=0;k<8;k++) sh[tid][k]+=sh[tid+s][k];
            }
            __syncthreads();
        }
        if (tid < 8) atomicAdd(&stats[tid], sh[0][tid]);
    } else {
        int r = (blockIdx.x - NSB)*256 + tid;
        float4 v = make_float4(0.f,0.f,0.f,0.f);
        if (r < NR) v = *(const float4*)(r_x + (size_t)r*8);
        sh[tid][0]=v.x; sh[tid][1]=v.y; sh[tid][2]=v.z;
        sh[tid][3]=v.x*v.x; sh[tid][4]=v.y*v.y; sh[tid][5]=v.z*v.z;
        sh[tid][6]=0.f; sh[tid][7]=0.f;
        __syncthreads();
        for (int s=128; s>0; s>>=1){
            if (tid < s){
                #pragma unroll
                for (int k=0;k<6;k++) sh[tid][k]+=sh[tid+s][k];
            }
            __syncthreads();
        }
        if (tid < 6) atomicAdd(&stats[8+tid], sh[0][tid]);
    }
}

__global__ void finalize_stats_kernel(float* __restrict__ st,
        const float* __restrict__ bn_s_w, const float* __restrict__ bn_s_b,
        const float* __restrict__ bn_r_w, const float* __restrict__ bn_r_b){
    int t = threadIdx.x;
    if (t < SC){
        float m  = st[t] * (1.f/NS);
        float var= st[4+t] * (1.f/NS) - m*m;
        float sc = rsqrtf(var + EPSV) * bn_s_w[t];
        st[16+t] = sc; st[20+t] = bn_s_b[t] - m*sc;
    } else if (t >= 8 && t < 8+RC){
        int k = t-8;
        float m  = st[8+k] * (1.f/NR);
        float var= st[11+k] * (1.f/NR) - m*m;
        float sc = rsqrtf(var + EPSV) * bn_r_w[k];
        st[24+k] = sc; st[27+k] = bn_r_b[k] - m*sc;
    }
}

// ---------------- node features (writes xb, panel-swizzled) ----------------
// block = one 16-node panel; thread tid: node m = tid&15, chunk l = tid>>4
// (channels l*8..l*8+7); writes one uint4 chunk -> block writes its whole
// 4KB panel fully coalesced.
__global__ __launch_bounds__(256) void feature_kernel(const float* __restrict__ s_x,
        const float* __restrict__ r_x, const float* __restrict__ stats,
        const float* __restrict__ lin_s_w, const float* __restrict__ lin_r_w,
        unsigned short* __restrict__ xb){
    int p = blockIdx.x;
    int tid = threadIdx.x;
    int m = tid & 15;
    int l = tid >> 4;
    int c0 = l*8;
    int node = p*16 + m;
    int b = node / SR;
    int pp = node - b*SR;
    float a[8];
    if (pp < SDIM){
        int row = b*SDIM + pp;
        float4 v = *(const float4*)(s_x + (size_t)row*SC);
        float i0 = v.x*stats[16]+stats[20];
        float i1 = v.y*stats[17]+stats[21];
        float i2 = v.z*stats[18]+stats[22];
        float i3 = v.w*stats[19]+stats[23];
        #pragma unroll
        for (int k=0;k<8;k++)
            a[k] = i0*lin_s_w[c0+k] + i1*lin_s_w[HC+c0+k]
                 + i2*lin_s_w[2*HC+c0+k] + i3*lin_s_w[3*HC+c0+k];
    } else {
        int row = b*RDIM + (pp - SDIM);
        float4 v = *(const float4*)(r_x + (size_t)row*8);
        float i0 = v.x*stats[24]+stats[27];
        float i1 = v.y*stats[25]+stats[28];
        float i2 = v.z*stats[26]+stats[29];
        #pragma unroll
        for (int k=0;k<8;k++)
            a[k] = i0*lin_r_w[c0+k] + i1*lin_r_w[HC+c0+k] + i2*lin_r_w[2*HC+c0+k];
    }
    uint4 pk;
    pk.x = (unsigned)f2bf(leaky(a[0])) | ((unsigned)f2bf(leaky(a[1])) << 16);
    pk.y = (unsigned)f2bf(leaky(a[2])) | ((unsigned)f2bf(leaky(a[3])) << 16);
    pk.z = (unsigned)f2bf(leaky(a[4])) | ((unsigned)f2bf(leaky(a[5])) << 16);
    pk.w = (unsigned)f2bf(leaky(a[6])) | ((unsigned)f2bf(leaky(a[7])) << 16);
    // chunk addr: p*2048 + ks*512 + q*128 + m*8 with l = ks*4+q  ->  p*2048 + tid'*8
    // where tid' = (l>>2)*64 + (l&3)*16 + m
    size_t elem = (size_t)p*2048 + (size_t)((l>>2)*512 + (l&3)*128 + m*8);
    *(uint4*)(xb + elem) = pk;
}

// ---------------- CSR build, bucketed ----------------
__global__ __launch_bounds__(256) void bucket_kernel(const int* __restrict__ src,
        const int* __restrict__ dst, int* __restrict__ bcnt,
        unsigned* __restrict__ bedge){
    __shared__ int hist[NBUK];
    __shared__ int cur[NBUK];
    int tid = threadIdx.x;
    int e0 = blockIdx.x * BK_EDGES;
    for (int b = tid; b < NBUK; b += 256) hist[b] = 0;
    __syncthreads();
    for (int j = tid; j < BK_EDGES; j += 256){
        int d = dst[e0 + j];
        atomicAdd(&hist[d >> 8], 1);
    }
    __syncthreads();
    for (int b = tid; b < NBUK; b += 256){
        int c = hist[b];
        cur[b] = (c > 0) ? atomicAdd(&bcnt[b], c) : 0;
    }
    __syncthreads();
    for (int j = tid; j < BK_EDGES; j += 256){
        int d = dst[e0 + j];
        int s = src[e0 + j];
        int b = d >> 8;
        int pos = atomicAdd(&cur[b], 1);
        bedge[(size_t)b*BCAP + pos] = ((unsigned)s << 8) | (unsigned)(d & 255);
    }
}

// Phase B1: per-bucket LDS histogram -> rp, dinv; inline bucket-base prefix
__global__ __launch_bounds__(256) void hist_kernel(const int* __restrict__ bcnt,
        int* __restrict__ bbase, const unsigned* __restrict__ bedge,
        int* __restrict__ rp, float* __restrict__ dinv){
    __shared__ int h[256];
    __shared__ int sc[256];
    __shared__ int pre[256];
    int b = blockIdx.x, tid = threadIdx.x;
    int ps = 0;
    for (int i = tid; i < NBUK; i += 256)
        if (i < b) ps += bcnt[i];
    pre[tid] = ps;
    h[tid] = 0;
    __syncthreads();
    for (int s=128; s>0; s>>=1){
        if (tid < s) pre[tid] += pre[tid+s];
        __syncthreads();
    }
    int base = pre[0];
    int n = bcnt[b];
    const unsigned* be = bedge + (size_t)b*BCAP;
    for (int j = tid; j < n; j += 256)
        atomicAdd(&h[be[j] & 255u], 1);
    __syncthreads();
    int v = h[tid];
    sc[tid] = v;
    __syncthreads();
    for (int off=1; off<256; off<<=1){
        int t = (tid >= off) ? sc[tid-off] : 0;
        __syncthreads();
        sc[tid] += t;
        __syncthreads();
    }
    int node = b*256 + tid;
    rp[node] = base + sc[tid] - v;
    dinv[node] = rsqrtf((float)(v + 1));        // +1 self loop
    if (tid == 0) bbase[b] = base;
    if (b == NBUK-1 && tid == 0) rp[NN] = EE;
}

// Phase B2: per-bucket LDS scatter into staging, then coalesced stream-out.
// csr entry = (src*HC byte offset into fp8 xw, weight)
__global__ __launch_bounds__(256) void build_kernel(const int* __restrict__ bcnt,
        const int* __restrict__ bbase, const unsigned* __restrict__ bedge,
        const int* __restrict__ rp, const float* __restrict__ dinv,
        int2* __restrict__ csr){
    __shared__ int cur[256];
    __shared__ float dlocal[256];
    __shared__ int2 stage[BCAP];
    int b = blockIdx.x, tid = threadIdx.x;
    int base = bbase[b];
    cur[tid] = rp[b*256 + tid] - base;
    dlocal[tid] = dinv[b*256 + tid];
    __syncthreads();
    int n = bcnt[b];
    const unsigned* be = bedge + (size_t)b*BCAP;
    for (int j = tid; j < n; j += 256){
        unsigned e = be[j];
        int dl = (int)(e & 255u);
        int s  = (int)(e >> 8);
        float w = dinv[s] * dlocal[dl];
        int pos = atomicAdd(&cur[dl], 1);
        stage[pos] = make_int2((int)((e & ~255u) >> 1), __float_as_int(w)); // s*HC
    }
    __syncthreads();
    int2* seg = csr + base;
    for (int j = tid; j < n; j += 256)
        seg[j] = stage[j];
}

// ---------------- W pre-swizzle: fp32 [k][n] -> bf16 B-fragment layout ----------------
__global__ void wswz_kernel(const float* __restrict__ conv_w, uint4* __restrict__ wswz){
    int l = blockIdx.x;
    const float* Wg = conv_w + (size_t)l*HC*HC;
    int tid = threadIdx.x;
    #pragma unroll
    for (int i=0;i<8;i++){
        int slot = tid + i*256;       // 0..2047
        int g = slot >> 6;            // nt*4+ks
        int ln = slot & 63;
        int nt = g >> 2, ks = g & 3;
        int q = ln >> 4, n = nt*16 + (ln & 15);
        int k0 = ks*32 + q*8;
        unsigned short h[8];
        #pragma unroll
        for (int j=0;j<8;j++) h[j] = f2bf(Wg[(size_t)(k0+j)*HC + n]);
        uint4 o;
        o.x = (unsigned)h[0] | ((unsigned)h[1]<<16);
        o.y = (unsigned)h[2] | ((unsigned)h[3]<<16);
        o.z = (unsigned)h[4] | ((unsigned)h[5]<<16);
        o.w = (unsigned)h[6] | ((unsigned)h[7]<<16);
        wswz[(size_t)l*2048 + slot] = o;
    }
}

// ---------------- conv GEMM: xw(fp8) = xb(bf16, panel-swizzled) @ W ----------------
// 128 rows per block; A-loads are contiguous 1KB wave-loads from the
// panel-swizzled xb; bf16 LDS staging, fp8 HW-convert on stream-out.
__global__ __launch_bounds__(256) void gemm_kernel(const unsigned short* __restrict__ xb,
        const uint4* __restrict__ wswz, unsigned char* __restrict__ xw){
    __shared__ uint4 Wlds[2048];              // 32 KB, B-frag layout
    __shared__ unsigned short outb[64*136];   // 17 KB, pitch 136
    int tid = threadIdx.x;
    #pragma unroll
    for (int i=0;i<8;i++){
        int slot = tid + i*256;
        Wlds[slot] = wswz[slot];
    }
    int lane = tid & 63, w = tid >> 6;
    int q = lane >> 4, m = lane & 15;
    v4f acc[2][8];
    #pragma unroll
    for (int rg=0;rg<2;rg++)
        #pragma unroll
        for (int nt=0;nt<8;nt++) acc[rg][nt] = (v4f){0.f,0.f,0.f,0.f};
    __syncthreads();
    #pragma unroll
    for (int rg=0; rg<2; rg++){
        int p = blockIdx.x*8 + rg*4 + w;      // panel
        const v8s* apan = (const v8s*)(xb + (size_t)p*2048);
        #pragma unroll
        for (int ks=0; ks<4; ks++){
            v8s a = apan[ks*64 + lane];       // contiguous 1KB per wave
            #pragma unroll
            for (int nt=0;nt<8;nt++){
                v8s b = *(const v8s*)&Wlds[(nt*4+ks)*64 + lane];
                acc[rg][nt] = __builtin_amdgcn_mfma_f32_16x16x32_bf16(a, b, acc[rg][nt], 0, 0, 0);
            }
        }
    }
    int rowbase = blockIdx.x*128;
    #pragma unroll
    for (int rg=0; rg<2; rg++){
        #pragma unroll
        for (int nt=0;nt<8;nt++){
            #pragma unroll
            for (int i=0;i<4;i++){
                outb[(w*16 + q*4 + i)*136 + nt*16 + m] = f2bf(acc[rg][nt][i]);
            }
        }
        __syncthreads();
        size_t gbase = (size_t)(rowbase + rg*64) * HC;   // byte offset (1 B/elem)
        #pragma unroll
        for (int i=0;i<4;i++){
            int c = tid + i*256;
            int r = c >> 4, j = c & 15;
            uint4 v = *(const uint4*)&outb[r*136 + j*8];
            float4 lo = bf4_to_f4(make_uint2(v.x, v.y));
            float4 hi = bf4_to_f4(make_uint2(v.z, v.w));
            uint2 o;
            o.x = f4_to_fp8x4(lo.x, lo.y, lo.z, lo.w);
            o.y = f4_to_fp8x4(hi.x, hi.y, hi.z, hi.w);
            *(uint2*)&xw[gbase + (size_t)r*HC + j*8] = o;
        }
        __syncthreads();
    }
}

// ---------------- aggregation: xb += leaky(A_norm @ xw + b), xw fp8 ----------------
// 16 lanes x 8B per edge row; packed v2f accumulation (v_pk_fma_f32)
__global__ __launch_bounds__(256) void agg_kernel(const unsigned char* __restrict__ xw,
        const int* __restrict__ rp, const int2* __restrict__ csr,
        const float* __restrict__ dinv, const float* __restrict__ bias,
        unsigned short* __restrict__ xb, float* __restrict__ pooled){
    int lane = threadIdx.x & 63;
    int node = blockIdx.x*4 + (threadIdx.x >> 6);
    int g  = lane >> 4;             // edge offset within quad
    unsigned c8 = (lane & 15) * 8;  // channel octet (8 B in fp8)
    int beg = rp[node], end = rp[node+1];

    v2f a0[4] = {(v2f){0.f,0.f},(v2f){0.f,0.f},(v2f){0.f,0.f},(v2f){0.f,0.f}};
    v2f a1[4] = {(v2f){0.f,0.f},(v2f){0.f,0.f},(v2f){0.f,0.f},(v2f){0.f,0.f}};

    int j = beg + g;
    while (j + 4 < end){
        int2 e0 = csr[j];
        int2 e1 = csr[j+4];
        uint2 p0 = *(const uint2*)(xw + ((unsigned)e0.x + c8));
        uint2 p1 = *(const uint2*)(xw + ((unsigned)e1.x + c8));
        float w0 = __int_as_float(e0.y);
        float w1 = __int_as_float(e1.y);
        v2f w0v = (v2f){w0, w0};
        v2f w1v = (v2f){w1, w1};
        a0[0] += w0v * __builtin_amdgcn_cvt_pk_f32_fp8((int)p0.x, false);
        a0[1] += w0v * __builtin_amdgcn_cvt_pk_f32_fp8((int)p0.x, true);
        a0[2] += w0v * __builtin_amdgcn_cvt_pk_f32_fp8((int)p0.y, false);
        a0[3] += w0v * __builtin_amdgcn_cvt_pk_f32_fp8((int)p0.y, true);
        a1[0] += w1v * __builtin_amdgcn_cvt_pk_f32_fp8((int)p1.x, false);
        a1[1] += w1v * __builtin_amdgcn_cvt_pk_f32_fp8((int)p1.x, true);
        a1[2] += w1v * __builtin_amdgcn_cvt_pk_f32_fp8((int)p1.y, false);
        a1[3] += w1v * __builtin_amdgcn_cvt_pk_f32_fp8((int)p1.y, true);
        j += 8;
    }
    while (j < end){
        int2 e = csr[j];
        uint2 p = *(const uint2*)(xw + ((unsigned)e.x + c8));
        float w = __int_as_float(e.y);
        v2f wv = (v2f){w, w};
        a0[0] += wv * __builtin_amdgcn_cvt_pk_f32_fp8((int)p.x, false);
        a0[1] += wv * __builtin_amdgcn_cvt_pk_f32_fp8((int)p.x, true);
        a0[2] += wv * __builtin_amdgcn_cvt_pk_f32_fp8((int)p.y, false);
        a0[3] += wv * __builtin_amdgcn_cvt_pk_f32_fp8((int)p.y, true);
        j += 4;
    }
    #pragma unroll
    for (int k=0;k<4;k++) a0[k] += a1[k];
    // self loop on group 0 only
    if (g == 0){
        float dn = dinv[node];
        v2f sw = (v2f){dn*dn, dn*dn};
        uint2 p = *(const uint2*)(xw + ((unsigned)node*HC + c8));
        a0[0] += sw * __builtin_amdgcn_cvt_pk_f32_fp8((int)p.x, false);
        a0[1] += sw * __builtin_amdgcn_cvt_pk_f32_fp8((int)p.x, true);
        a0[2] += sw * __builtin_amdgcn_cvt_pk_f32_fp8((int)p.y, false);
        a0[3] += sw * __builtin_amdgcn_cvt_pk_f32_fp8((int)p.y, true);
    }
    // reduce across the 4 groups (xor 16, then xor 32)
    float r[8];
    #pragma unroll
    for (int k=0;k<4;k++){ r[2*k] = a0[k].x; r[2*k+1] = a0[k].y; }
    #pragma unroll
    for (int m2 = 16; m2 <= 32; m2 <<= 1){
        #pragma unroll
        for (int k=0;k<8;k++) r[k] += __shfl_xor(r[k], m2, 64);
    }
    if (g == 0){
        float4 bL = *(const float4*)(bias + c8);
        float4 bH = *(const float4*)(bias + c8 + 4);
        // panel-swizzled xb chunk for (node, channels c8..c8+7):
        size_t idx = (size_t)(node >> 4)*2048
                   + (size_t)(((lane >> 2)*512) + ((lane & 3)*128) + ((node & 15)*8));
        uint4 xp = *(const uint4*)(xb + idx);
        float4 xL = bf4_to_f4(make_uint2(xp.x, xp.y));
        float4 xH = bf4_to_f4(make_uint2(xp.z, xp.w));
        xL.x += leaky(r[0] + bL.x);
        xL.y += leaky(r[1] + bL.y);
        xL.z += leaky(r[2] + bL.z);
        xL.w += leaky(r[3] + bL.w);
        xH.x += leaky(r[4] + bH.x);
        xH.y += leaky(r[5] + bH.y);
        xH.z += leaky(r[6] + bH.z);
        xH.w += leaky(r[7] + bH.w);
        if (pooled == nullptr){
            uint4 pk;
            pk.x = (unsigned)f2bf(xL.x) | ((unsigned)f2bf(xL.y) << 16);
            pk.y = (unsigned)f2bf(xL.z) | ((unsigned)f2bf(xL.w) << 16);
            pk.z = (unsigned)f2bf(xH.x) | ((unsigned)f2bf(xH.y) << 16);
            pk.w = (unsigned)f2bf(xH.z) | ((unsigned)f2bf(xH.w) << 16);
            *(uint4*)(xb + idx) = pk;
        } else {
            // fused channel-mean pool over the 16 lanes of group 0
            float s = xL.x + xL.y + xL.z + xL.w + xH.x + xH.y + xH.z + xH.w;
            #pragma unroll
            for (int m2 = 1; m2 < 16; m2 <<= 1)
                s += __shfl_xor(s, m2, 64);   // sources stay within lanes 0..15
            if (lane == 0) pooled[node] = s * (1.f/128.f);
        }
    }
}

// ---------------- heads: z, o, output ----------------
__global__ void head_kernel(const float* __restrict__ pooled, const float* __restrict__ r_x,
        const float* __restrict__ linr_w, const float* __restrict__ linr_b,
        const float* __restrict__ lino_w1, const float* __restrict__ lino_b1,
        const float* __restrict__ lino_w2, const float* __restrict__ lino_b2,
        float* __restrict__ out){
    int b = blockIdx.x, tid = threadIdx.x;
    __shared__ float red[128][8];
    __shared__ float hsh[128];
    __shared__ float zsh[8];
    float part[NO];
    #pragma unroll
    for (int j=0;j<NO;j++) part[j]=0.f;
    for (int i = tid; i < SR; i += 128){
        float pv = pooled[(size_t)b*SR + i];
        #pragma unroll
        for (int j=0;j<NO;j++) part[j] += pv * linr_w[i*NO + j];
    }
    #pragma unroll
    for (int j=0;j<NO;j++) red[tid][j] = part[j];
    const float* ox = r_x + (size_t)b*RDIM*8 + RC;
    float hv = lino_b1[tid];
    #pragma unroll
    for (int k=0;k<5;k++) hv += ox[k]*lino_w1[k*HC + tid];
    hsh[tid] = leaky(hv);
    __syncthreads();
    for (int s=64; s>0; s>>=1){
        if (tid < s){
            #pragma unroll
            for (int j=0;j<NO;j++) red[tid][j] += red[tid+s][j];
        }
        __syncthreads();
    }
    if (tid < NO) zsh[tid] = expf(red[0][tid] + linr_b[tid]);
    __syncthreads();
    if (tid < NO){
        float zsum = 0.f;
        #pragma unroll
        for (int j=0;j<NO;j++) zsum += zsh[j];
        float z = zsh[tid] / (zsum + 1.f);
        float o = lino_b2[tid];
        for (int cc=0; cc<HC; cc++) o += hsh[cc]*lino_w2[cc*NO + tid];
        out[b*NO + tid] = z * expf(o);
    }
}

extern "C" void kernel_launch(void* const* d_in, const int* in_sizes, int n_in,
                              void* d_out, int out_size, void* d_ws, size_t ws_size,
                              hipStream_t stream) {
    const float* s_x     = (const float*)d_in[0];
    const float* r_x     = (const float*)d_in[1];
    const int*   ei      = (const int*)d_in[2];
    const float* bn_s_w  = (const float*)d_in[3];
    const float* bn_s_b  = (const float*)d_in[4];
    const float* bn_r_w  = (const float*)d_in[5];
    const float* bn_r_b  = (const float*)d_in[6];
    const float* lin_s_w = (const float*)d_in[7];
    const float* lin_r_w = (const float*)d_in[8];
    const float* conv_w  = (const float*)d_in[9];
    const float* conv_b  = (const float*)d_in[10];
    const float* linr_w  = (const float*)d_in[11];
    const float* linr_b  = (const float*)d_in[12];
    const float* lino_w1 = (const float*)d_in[13];
    const float* lino_b1 = (const float*)d_in[14];
    const float* lino_w2 = (const float*)d_in[15];
    const float* lino_b2 = (const float*)d_in[16];
    float* out = (float*)d_out;

    char* ws = (char*)d_ws;
    size_t off = 0;
    auto alloc = [&](size_t bytes)->void*{
        void* p = ws + off;
        off = (off + bytes + 255) & ~(size_t)255;
        return p;
    };
    unsigned short* xb = (unsigned short*)alloc((size_t)NN*HC*2);
    unsigned char*  xw = (unsigned char*) alloc((size_t)NN*HC);
    float* dinv     = (float*)alloc((size_t)NN*4);
    int*   rp       = (int*)  alloc((size_t)(NN+1)*4);
    int2*  csr      = (int2*) alloc((size_t)EE*8);
    unsigned* bedge = (unsigned*)alloc((size_t)NBUK*BCAP*4);
    int*   bcnt     = (int*)  alloc((size_t)NBUK*4);
    int*   bbase    = (int*)  alloc((size_t)NBUK*4);
    float* stats    = (float*)alloc(64*4);
    float* pooled   = (float*)alloc((size_t)NN*4);
    uint4* wswz     = (uint4*)alloc((size_t)LCONV*2048*16);

    hipMemsetAsync(bcnt, 0, (size_t)NBUK*4, stream);
    hipMemsetAsync(stats, 0, 64*4, stream);

    stats_kernel<<<NSB + (NR+255)/256, 256, 0, stream>>>(s_x, r_x, stats);
    finalize_stats_kernel<<<1, 64, 0, stream>>>(stats, bn_s_w, bn_s_b, bn_r_w, bn_r_b);
    feature_kernel<<<NN/16, 256, 0, stream>>>(s_x, r_x, stats, lin_s_w, lin_r_w, xb);
    wswz_kernel<<<LCONV, 256, 0, stream>>>(conv_w, wswz);

    bucket_kernel<<<BK_BLOCKS, 256, 0, stream>>>(ei, ei + EE, bcnt, bedge);
    hist_kernel<<<NBUK, 256, 0, stream>>>(bcnt, bbase, bedge, rp, dinv);
    build_kernel<<<NBUK, 256, 0, stream>>>(bcnt, bbase, bedge, rp, dinv, csr);

    for (int l = 0; l < LCONV; l++){
        gemm_kernel<<<NN/128, 256, 0, stream>>>(xb, wswz + (size_t)l*2048, xw);
        agg_kernel<<<NN/4, 256, 0, stream>>>(xw, rp, csr, dinv, conv_b + (size_t)l*HC,
                                             xb, (l == LCONV-1) ? pooled : nullptr);
    }

    head_kernel<<<BATCH, 128, 0, stream>>>(pooled, r_x, linr_w, linr_b,
                                           lino_w1, lino_b1, lino_w2, lino_b2, out);
}

// Round 13
// 728.190 us; speedup vs baseline: 1.0252x; 1.0252x over previous
//
#include <hip/hip_runtime.h>
#include <hip/hip_bf16.h>

#define SDIM 38
#define RDIM 340
#define HC   128
#define SC   4
#define RC   3
#define NO   7
#define LCONV 4
#define BATCH 512
#define SR   378
#define NN   (BATCH*SR)     // 193536
#define NS   (BATCH*SDIM)   // 19456
#define NR   (BATCH*RDIM)   // 174080
#define EE   3072000
#define EPSV 1e-5f
#define NBUK 756            // NN/256 exactly
#define BCAP 4800           // bucket capacity; mean 4064, sigma 64
#define BK_BLOCKS 256
#define BK_EDGES  12000     // 256*12000 = 3,072,000 = EE
#define NSB 76              // ceil(NS/256)

typedef short v8s __attribute__((ext_vector_type(8)));
typedef float v4f __attribute__((ext_vector_type(4)));
typedef float v2f __attribute__((ext_vector_type(2)));

__device__ __forceinline__ float leaky(float v){ return v > 0.f ? v : 0.2f*v; }

// round-to-nearest-even fp32 -> bf16 (as ushort)
__device__ __forceinline__ unsigned short f2bf(float f){
    union { float f; unsigned u; } v; v.f = f;
    unsigned r = v.u + 0x7fffu + ((v.u >> 16) & 1u);
    return (unsigned short)(r >> 16);
}
// unpack 4 bf16 (uint2) -> float4
__device__ __forceinline__ float4 bf4_to_f4(uint2 p){
    float4 r;
    r.x = __uint_as_float(p.x << 16);
    r.y = __uint_as_float(p.x & 0xffff0000u);
    r.z = __uint_as_float(p.y << 16);
    r.w = __uint_as_float(p.y & 0xffff0000u);
    return r;
}
// unpack 4 fp8 e4m3 (bytes of uint) -> float4  (HW convert)
__device__ __forceinline__ float4 fp8x4_to_f4(unsigned u){
    v2f lo = __builtin_amdgcn_cvt_pk_f32_fp8((int)u, false);
    v2f hi = __builtin_amdgcn_cvt_pk_f32_fp8((int)u, true);
    return make_float4(lo.x, lo.y, hi.x, hi.y);
}
// pack 4 fp32 -> 4 fp8 e4m3 bytes (HW convert)
__device__ __forceinline__ unsigned f4_to_fp8x4(float a, float b, float c, float d){
    int v = 0;
    v = __builtin_amdgcn_cvt_pk_fp8_f32(a, b, v, false);
    v = __builtin_amdgcn_cvt_pk_fp8_f32(c, d, v, true);
    return (unsigned)v;
}

// ---------------- batchnorm stats (fused s + r) ----------------
__global__ void stats_kernel(const float* __restrict__ s_x, const float* __restrict__ r_x,
                             float* __restrict__ stats){
    int tid = threadIdx.x;
    __shared__ float sh[256][8];
    if (blockIdx.x < NSB){
        int r = blockIdx.x*256 + tid;
        float4 v = make_float4(0.f,0.f,0.f,0.f);
        if (r < NS) v = *(const float4*)(s_x + (size_t)r*SC);
        sh[tid][0]=v.x; sh[tid][1]=v.y; sh[tid][2]=v.z; sh[tid][3]=v.w;
        sh[tid][4]=v.x*v.x; sh[tid][5]=v.y*v.y; sh[tid][6]=v.z*v.z; sh[tid][7]=v.w*v.w;
        __syncthreads();
        for (int s=128; s>0; s>>=1){
            if (tid < s){
                #pragma unroll
                for (int k=0;k<8;k++) sh[tid][k]+=sh[tid+s][k];
            }
            __syncthreads();
        }
        if (tid < 8) atomicAdd(&stats[tid], sh[0][tid]);
    } else {
        int r = (blockIdx.x - NSB)*256 + tid;
        float4 v = make_float4(0.f,0.f,0.f,0.f);
        if (r < NR) v = *(const float4*)(r_x + (size_t)r*8);
        sh[tid][0]=v.x; sh[tid][1]=v.y; sh[tid][2]=v.z;
        sh[tid][3]=v.x*v.x; sh[tid][4]=v.y*v.y; sh[tid][5]=v.z*v.z;
        sh[tid][6]=0.f; sh[tid][7]=0.f;
        __syncthreads();
        for (int s=128; s>0; s>>=1){
            if (tid < s){
                #pragma unroll
                for (int k=0;k<6;k++) sh[tid][k]+=sh[tid+s][k];
            }
            __syncthreads();
        }
        if (tid < 6) atomicAdd(&stats[8+tid], sh[0][tid]);
    }
}

__global__ void finalize_stats_kernel(float* __restrict__ st,
        const float* __restrict__ bn_s_w, const float* __restrict__ bn_s_b,
        const float* __restrict__ bn_r_w, const float* __restrict__ bn_r_b){
    int t = threadIdx.x;
    if (t < SC){
        float m  = st[t] * (1.f/NS);
        float var= st[4+t] * (1.f/NS) - m*m;
        float sc = rsqrtf(var + EPSV) * bn_s_w[t];
        st[16+t] = sc; st[20+t] = bn_s_b[t] - m*sc;
    } else if (t >= 8 && t < 8+RC){
        int k = t-8;
        float m  = st[8+k] * (1.f/NR);
        float var= st[11+k] * (1.f/NR) - m*m;
        float sc = rsqrtf(var + EPSV) * bn_r_w[k];
        st[24+k] = sc; st[27+k] = bn_r_b[k] - m*sc;
    }
}

// ---------------- node features (writes xb bf16, row-major) ----------------
__global__ void feature_kernel(const float* __restrict__ s_x, const float* __restrict__ r_x,
        const float* __restrict__ stats, const float* __restrict__ lin_s_w,
        const float* __restrict__ lin_r_w, unsigned short* __restrict__ xb){
    int node = blockIdx.x*4 + (threadIdx.x >> 6);
    int c0 = (threadIdx.x & 63) * 2;
    int b = node / SR;
    int p = node - b*SR;
    float a0, a1;
    if (p < SDIM){
        int row = b*SDIM + p;
        float4 v = *(const float4*)(s_x + (size_t)row*SC);
        float i0 = v.x*stats[16]+stats[20];
        float i1 = v.y*stats[17]+stats[21];
        float i2 = v.z*stats[18]+stats[22];
        float i3 = v.w*stats[19]+stats[23];
        a0 = i0*lin_s_w[c0] + i1*lin_s_w[HC+c0] + i2*lin_s_w[2*HC+c0] + i3*lin_s_w[3*HC+c0];
        a1 = i0*lin_s_w[c0+1] + i1*lin_s_w[HC+c0+1] + i2*lin_s_w[2*HC+c0+1] + i3*lin_s_w[3*HC+c0+1];
    } else {
        int row = b*RDIM + (p - SDIM);
        float4 v = *(const float4*)(r_x + (size_t)row*8);
        float i0 = v.x*stats[24]+stats[27];
        float i1 = v.y*stats[25]+stats[28];
        float i2 = v.z*stats[26]+stats[29];
        a0 = i0*lin_r_w[c0] + i1*lin_r_w[HC+c0] + i2*lin_r_w[2*HC+c0];
        a1 = i0*lin_r_w[c0+1] + i1*lin_r_w[HC+c0+1] + i2*lin_r_w[2*HC+c0+1];
    }
    a0 = leaky(a0); a1 = leaky(a1);
    unsigned pk = (unsigned)f2bf(a0) | ((unsigned)f2bf(a1) << 16);
    *(unsigned*)(xb + (size_t)node*HC + c0) = pk;
}

// ---------------- CSR build, bucketed ----------------
__global__ __launch_bounds__(256) void bucket_kernel(const int* __restrict__ src,
        const int* __restrict__ dst, int* __restrict__ bcnt,
        unsigned* __restrict__ bedge){
    __shared__ int hist[NBUK];
    __shared__ int cur[NBUK];
    int tid = threadIdx.x;
    int e0 = blockIdx.x * BK_EDGES;
    for (int b = tid; b < NBUK; b += 256) hist[b] = 0;
    __syncthreads();
    for (int j = tid; j < BK_EDGES; j += 256){
        int d = dst[e0 + j];
        atomicAdd(&hist[d >> 8], 1);
    }
    __syncthreads();
    for (int b = tid; b < NBUK; b += 256){
        int c = hist[b];
        cur[b] = (c > 0) ? atomicAdd(&bcnt[b], c) : 0;
    }
    __syncthreads();
    for (int j = tid; j < BK_EDGES; j += 256){
        int d = dst[e0 + j];
        int s = src[e0 + j];
        int b = d >> 8;
        int pos = atomicAdd(&cur[b], 1);
        bedge[(size_t)b*BCAP + pos] = ((unsigned)s << 8) | (unsigned)(d & 255);
    }
}

// Phase B1: per-bucket LDS histogram -> rp, dinv; inline bucket-base prefix
__global__ __launch_bounds__(256) void hist_kernel(const int* __restrict__ bcnt,
        int* __restrict__ bbase, const unsigned* __restrict__ bedge,
        int* __restrict__ rp, float* __restrict__ dinv){
    __shared__ int h[256];
    __shared__ int sc[256];
    __shared__ int pre[256];
    int b = blockIdx.x, tid = threadIdx.x;
    int ps = 0;
    for (int i = tid; i < NBUK; i += 256)
        if (i < b) ps += bcnt[i];
    pre[tid] = ps;
    h[tid] = 0;
    __syncthreads();
    for (int s=128; s>0; s>>=1){
        if (tid < s) pre[tid] += pre[tid+s];
        __syncthreads();
    }
    int base = pre[0];
    int n = bcnt[b];
    const unsigned* be = bedge + (size_t)b*BCAP;
    for (int j = tid; j < n; j += 256)
        atomicAdd(&h[be[j] & 255u], 1);
    __syncthreads();
    int v = h[tid];
    sc[tid] = v;
    __syncthreads();
    for (int off=1; off<256; off<<=1){
        int t = (tid >= off) ? sc[tid-off] : 0;
        __syncthreads();
        sc[tid] += t;
        __syncthreads();
    }
    int node = b*256 + tid;
    rp[node] = base + sc[tid] - v;
    dinv[node] = rsqrtf((float)(v + 1));        // +1 self loop
    if (tid == 0) bbase[b] = base;
    if (b == NBUK-1 && tid == 0) rp[NN] = EE;
}

// Phase B2: per-bucket LDS scatter into staging, then coalesced stream-out.
// csr entry = (src*HC byte offset into fp8 xw, weight)
__global__ __launch_bounds__(256) void build_kernel(const int* __restrict__ bcnt,
        const int* __restrict__ bbase, const unsigned* __restrict__ bedge,
        const int* __restrict__ rp, const float* __restrict__ dinv,
        int2* __restrict__ csr){
    __shared__ int cur[256];
    __shared__ float dlocal[256];
    __shared__ int2 stage[BCAP];
    int b = blockIdx.x, tid = threadIdx.x;
    int base = bbase[b];
    cur[tid] = rp[b*256 + tid] - base;
    dlocal[tid] = dinv[b*256 + tid];
    __syncthreads();
    int n = bcnt[b];
    const unsigned* be = bedge + (size_t)b*BCAP;
    for (int j = tid; j < n; j += 256){
        unsigned e = be[j];
        int dl = (int)(e & 255u);
        int s  = (int)(e >> 8);
        float w = dinv[s] * dlocal[dl];
        int pos = atomicAdd(&cur[dl], 1);
        stage[pos] = make_int2((int)((e & ~255u) >> 1), __float_as_int(w)); // s*HC
    }
    __syncthreads();
    int2* seg = csr + base;
    for (int j = tid; j < n; j += 256)
        seg[j] = stage[j];
}

// ---------------- W pre-swizzle: fp32 [k][n] -> bf16 B-fragment layout ----------------
// COLUMN-PERMUTED: MFMA col (nt, mm) sources W channel mm*8+nt, so that gemm's
// C-layout register values (lane mm holds nt=0..7) pack into 8 consecutive fp8
// bytes of a natural-channel-order output row. (agg/bias indexing unchanged.)
__global__ void wswz_kernel(const float* __restrict__ conv_w, uint4* __restrict__ wswz){
    int l = blockIdx.x;
    const float* Wg = conv_w + (size_t)l*HC*HC;
    int tid = threadIdx.x;
    #pragma unroll
    for (int i=0;i<8;i++){
        int slot = tid + i*256;       // 0..2047
        int g = slot >> 6;            // nt*4+ks
        int ln = slot & 63;
        int nt = g >> 2, ks = g & 3;
        int q = ln >> 4;
        int ch = (ln & 15)*8 + nt;    // permuted source column
        int k0 = ks*32 + q*8;
        unsigned short h[8];
        #pragma unroll
        for (int j=0;j<8;j++) h[j] = f2bf(Wg[(size_t)(k0+j)*HC + ch]);
        uint4 o;
        o.x = (unsigned)h[0] | ((unsigned)h[1]<<16);
        o.y = (unsigned)h[2] | ((unsigned)h[3]<<16);
        o.z = (unsigned)h[4] | ((unsigned)h[5]<<16);
        o.w = (unsigned)h[6] | ((unsigned)h[7]<<16);
        wswz[(size_t)l*2048 + slot] = o;
    }
}

// ---------------- conv GEMM: xw(fp8) = xb(bf16) @ W (MFMA 16x16x32) ----------------
// 256 rows per block (4 row-groups of 64); W staged once (32 KB, only LDS).
// Direct register->fp8 epilogue: lane (q,m) holds C rows q*4+i, its 8 nt-values
// pack to bytes m*8..m*8+7 of the natural-channel-order output row.
__global__ __launch_bounds__(256) void gemm_kernel(const unsigned short* __restrict__ xb,
        const uint4* __restrict__ wswz, unsigned char* __restrict__ xw){
    __shared__ uint4 Wlds[2048];              // 32 KB, B-frag layout (col-permuted)
    int tid = threadIdx.x;
    #pragma unroll
    for (int i=0;i<8;i++){
        int slot = tid + i*256;
        Wlds[slot] = wswz[slot];
    }
    int lane = tid & 63, w = tid >> 6;
    int q = lane >> 4, m = lane & 15;
    int rowbase = blockIdx.x*256;
    __syncthreads();
    #pragma unroll
    for (int rg=0; rg<4; rg++){
        int row = rowbase + rg*64 + w*16 + m;
        const v8s* arow = (const v8s*)(xb + (size_t)row*HC + q*8);
        v4f acc[8];
        #pragma unroll
        for (int nt=0;nt<8;nt++) acc[nt] = (v4f){0.f,0.f,0.f,0.f};
        #pragma unroll
        for (int ks=0; ks<4; ks++){
            v8s a = arow[ks*4];
            #pragma unroll
            for (int nt=0;nt<8;nt++){
                v8s b = *(const v8s*)&Wlds[(nt*4+ks)*64 + lane];
                acc[nt] = __builtin_amdgcn_mfma_f32_16x16x32_bf16(a, b, acc[nt], 0, 0, 0);
            }
        }
        size_t gbase = (size_t)(rowbase + rg*64 + w*16) * HC;  // byte offsets (1 B/elem)
        #pragma unroll
        for (int i=0;i<4;i++){
            uint2 o;
            o.x = f4_to_fp8x4(acc[0][i], acc[1][i], acc[2][i], acc[3][i]);
            o.y = f4_to_fp8x4(acc[4][i], acc[5][i], acc[6][i], acc[7][i]);
            *(uint2*)&xw[gbase + (size_t)(q*4 + i)*HC + m*8] = o;
        }
    }
}

// ---------------- aggregation: xb += leaky(A_norm @ xw + b), xw fp8 ----------------
// 16 lanes x 8B per edge row (128 B fp8 row = 2 cache lines)
__global__ __launch_bounds__(256) void agg_kernel(const unsigned char* __restrict__ xw,
        const int* __restrict__ rp, const int2* __restrict__ csr,
        const float* __restrict__ dinv, const float* __restrict__ bias,
        unsigned short* __restrict__ xb, float* __restrict__ pooled){
    int lane = threadIdx.x & 63;
    int node = blockIdx.x*4 + (threadIdx.x >> 6);
    int g  = lane >> 4;             // edge offset within quad
    unsigned c8 = (lane & 15) * 8;  // channel octet (8 B in fp8)
    int beg = rp[node], end = rp[node+1];

    float4 aL0 = make_float4(0.f,0.f,0.f,0.f), aH0 = aL0;
    float4 aL1 = aL0, aH1 = aL0;

    int j = beg + g;
    while (j + 4 < end){
        int2 e0 = csr[j];
        int2 e1 = csr[j+4];
        uint2 p0 = *(const uint2*)(xw + ((unsigned)e0.x + c8));
        uint2 p1 = *(const uint2*)(xw + ((unsigned)e1.x + c8));
        float w0 = __int_as_float(e0.y);
        float w1 = __int_as_float(e1.y);
        float4 lo0 = fp8x4_to_f4(p0.x);
        float4 hi0 = fp8x4_to_f4(p0.y);
        float4 lo1 = fp8x4_to_f4(p1.x);
        float4 hi1 = fp8x4_to_f4(p1.y);
        aL0.x += w0*lo0.x; aL0.y += w0*lo0.y; aL0.z += w0*lo0.z; aL0.w += w0*lo0.w;
        aH0.x += w0*hi0.x; aH0.y += w0*hi0.y; aH0.z += w0*hi0.z; aH0.w += w0*hi0.w;
        aL1.x += w1*lo1.x; aL1.y += w1*lo1.y; aL1.z += w1*lo1.z; aL1.w += w1*lo1.w;
        aH1.x += w1*hi1.x; aH1.y += w1*hi1.y; aH1.z += w1*hi1.z; aH1.w += w1*hi1.w;
        j += 8;
    }
    while (j < end){
        int2 e = csr[j];
        uint2 p = *(const uint2*)(xw + ((unsigned)e.x + c8));
        float w = __int_as_float(e.y);
        float4 lo = fp8x4_to_f4(p.x);
        float4 hi = fp8x4_to_f4(p.y);
        aL0.x += w*lo.x; aL0.y += w*lo.y; aL0.z += w*lo.z; aL0.w += w*lo.w;
        aH0.x += w*hi.x; aH0.y += w*hi.y; aH0.z += w*hi.z; aH0.w += w*hi.w;
        j += 4;
    }
    aL0.x += aL1.x; aL0.y += aL1.y; aL0.z += aL1.z; aL0.w += aL1.w;
    aH0.x += aH1.x; aH0.y += aH1.y; aH0.z += aH1.z; aH0.w += aH1.w;
    // self loop on group 0 only
    if (g == 0){
        float dn = dinv[node];
        float sw = dn*dn;
        uint2 p = *(const uint2*)(xw + ((unsigned)node*HC + c8));
        float4 lo = fp8x4_to_f4(p.x);
        float4 hi = fp8x4_to_f4(p.y);
        aL0.x += sw*lo.x; aL0.y += sw*lo.y; aL0.z += sw*lo.z; aL0.w += sw*lo.w;
        aH0.x += sw*hi.x; aH0.y += sw*hi.y; aH0.z += sw*hi.z; aH0.w += sw*hi.w;
    }
    // reduce across the 4 groups (xor 16, then xor 32)
    #pragma unroll
    for (int m2 = 16; m2 <= 32; m2 <<= 1){
        aL0.x += __shfl_xor(aL0.x, m2, 64);
        aL0.y += __shfl_xor(aL0.y, m2, 64);
        aL0.z += __shfl_xor(aL0.z, m2, 64);
        aL0.w += __shfl_xor(aL0.w, m2, 64);
        aH0.x += __shfl_xor(aH0.x, m2, 64);
        aH0.y += __shfl_xor(aH0.y, m2, 64);
        aH0.z += __shfl_xor(aH0.z, m2, 64);
        aH0.w += __shfl_xor(aH0.w, m2, 64);
    }
    if (g == 0){
        float4 bL = *(const float4*)(bias + c8);
        float4 bH = *(const float4*)(bias + c8 + 4);
        size_t idx = (size_t)node*HC + c8;
        uint4 xp = *(const uint4*)(xb + idx);
        float4 xL = bf4_to_f4(make_uint2(xp.x, xp.y));
        float4 xH = bf4_to_f4(make_uint2(xp.z, xp.w));
        xL.x += leaky(aL0.x + bL.x);
        xL.y += leaky(aL0.y + bL.y);
        xL.z += leaky(aL0.z + bL.z);
        xL.w += leaky(aL0.w + bL.w);
        xH.x += leaky(aH0.x + bH.x);
        xH.y += leaky(aH0.y + bH.y);
        xH.z += leaky(aH0.z + bH.z);
        xH.w += leaky(aH0.w + bH.w);
        if (pooled == nullptr){
            uint4 pk;
            pk.x = (unsigned)f2bf(xL.x) | ((unsigned)f2bf(xL.y) << 16);
            pk.y = (unsigned)f2bf(xL.z) | ((unsigned)f2bf(xL.w) << 16);
            pk.z = (unsigned)f2bf(xH.x) | ((unsigned)f2bf(xH.y) << 16);
            pk.w = (unsigned)f2bf(xH.z) | ((unsigned)f2bf(xH.w) << 16);
            *(uint4*)(xb + idx) = pk;
        } else {
            // fused channel-mean pool over the 16 lanes of group 0
            float s = xL.x + xL.y + xL.z + xL.w + xH.x + xH.y + xH.z + xH.w;
            #pragma unroll
            for (int m2 = 1; m2 < 16; m2 <<= 1)
                s += __shfl_xor(s, m2, 64);   // sources stay within lanes 0..15
            if (lane == 0) pooled[node] = s * (1.f/128.f);
        }
    }
}

// ---------------- heads: z, o, output ----------------
__global__ void head_kernel(const float* __restrict__ pooled, const float* __restrict__ r_x,
        const float* __restrict__ linr_w, const float* __restrict__ linr_b,
        const float* __restrict__ lino_w1, const float* __restrict__ lino_b1,
        const float* __restrict__ lino_w2, const float* __restrict__ lino_b2,
        float* __restrict__ out){
    int b = blockIdx.x, tid = threadIdx.x;
    __shared__ float red[128][8];
    __shared__ float hsh[128];
    __shared__ float zsh[8];
    float part[NO];
    #pragma unroll
    for (int j=0;j<NO;j++) part[j]=0.f;
    for (int i = tid; i < SR; i += 128){
        float pv = pooled[(size_t)b*SR + i];
        #pragma unroll
        for (int j=0;j<NO;j++) part[j] += pv * linr_w[i*NO + j];
    }
    #pragma unroll
    for (int j=0;j<NO;j++) red[tid][j] = part[j];
    const float* ox = r_x + (size_t)b*RDIM*8 + RC;
    float hv = lino_b1[tid];
    #pragma unroll
    for (int k=0;k<5;k++) hv += ox[k]*lino_w1[k*HC + tid];
    hsh[tid] = leaky(hv);
    __syncthreads();
    for (int s=64; s>0; s>>=1){
        if (tid < s){
            #pragma unroll
            for (int j=0;j<NO;j++) red[tid][j] += red[tid+s][j];
        }
        __syncthreads();
    }
    if (tid < NO) zsh[tid] = expf(red[0][tid] + linr_b[tid]);
    __syncthreads();
    if (tid < NO){
        float zsum = 0.f;
        #pragma unroll
        for (int j=0;j<NO;j++) zsum += zsh[j];
        float z = zsh[tid] / (zsum + 1.f);
        float o = lino_b2[tid];
        for (int cc=0; cc<HC; cc++) o += hsh[cc]*lino_w2[cc*NO + tid];
        out[b*NO + tid] = z * expf(o);
    }
}

extern "C" void kernel_launch(void* const* d_in, const int* in_sizes, int n_in,
                              void* d_out, int out_size, void* d_ws, size_t ws_size,
                              hipStream_t stream) {
    const float* s_x     = (const float*)d_in[0];
    const float* r_x     = (const float*)d_in[1];
    const int*   ei      = (const int*)d_in[2];
    const float* bn_s_w  = (const float*)d_in[3];
    const float* bn_s_b  = (const float*)d_in[4];
    const float* bn_r_w  = (const float*)d_in[5];
    const float* bn_r_b  = (const float*)d_in[6];
    const float* lin_s_w = (const float*)d_in[7];
    const float* lin_r_w = (const float*)d_in[8];
    const float* conv_w  = (const float*)d_in[9];
    const float* conv_b  = (const float*)d_in[10];
    const float* linr_w  = (const float*)d_in[11];
    const float* linr_b  = (const float*)d_in[12];
    const float* lino_w1 = (const float*)d_in[13];
    const float* lino_b1 = (const float*)d_in[14];
    const float* lino_w2 = (const float*)d_in[15];
    const float* lino_b2 = (const float*)d_in[16];
    float* out = (float*)d_out;

    char* ws = (char*)d_ws;
    size_t off = 0;
    auto alloc = [&](size_t bytes)->void*{
        void* p = ws + off;
        off = (off + bytes + 255) & ~(size_t)255;
        return p;
    };
    unsigned short* xb = (unsigned short*)alloc((size_t)NN*HC*2);
    unsigned char*  xw = (unsigned char*) alloc((size_t)NN*HC);
    float* dinv     = (float*)alloc((size_t)NN*4);
    int*   rp       = (int*)  alloc((size_t)(NN+1)*4);
    int2*  csr      = (int2*) alloc((size_t)EE*8);
    unsigned* bedge = (unsigned*)alloc((size_t)NBUK*BCAP*4);
    int*   bcnt     = (int*)  alloc((size_t)NBUK*4);
    int*   bbase    = (int*)  alloc((size_t)NBUK*4);
    float* stats    = (float*)alloc(64*4);
    float* pooled   = (float*)alloc((size_t)NN*4);
    uint4* wswz     = (uint4*)alloc((size_t)LCONV*2048*16);

    hipMemsetAsync(bcnt, 0, (size_t)NBUK*4, stream);
    hipMemsetAsync(stats, 0, 64*4, stream);

    stats_kernel<<<NSB + (NR+255)/256, 256, 0, stream>>>(s_x, r_x, stats);
    finalize_stats_kernel<<<1, 64, 0, stream>>>(stats, bn_s_w, bn_s_b, bn_r_w, bn_r_b);
    feature_kernel<<<NN/4, 256, 0, stream>>>(s_x, r_x, stats, lin_s_w, lin_r_w, xb);
    wswz_kernel<<<LCONV, 256, 0, stream>>>(conv_w, wswz);

    bucket_kernel<<<BK_BLOCKS, 256, 0, stream>>>(ei, ei + EE, bcnt, bedge);
    hist_kernel<<<NBUK, 256, 0, stream>>>(bcnt, bbase, bedge, rp, dinv);
    build_kernel<<<NBUK, 256, 0, stream>>>(bcnt, bbase, bedge, rp, dinv, csr);

    for (int l = 0; l < LCONV; l++){
        gemm_kernel<<<NN/256, 256, 0, stream>>>(xb, wswz + (size_t)l*2048, xw);
        agg_kernel<<<NN/4, 256, 0, stream>>>(xw, rp, csr, dinv, conv_b + (size_t)l*HC,
                                             xb, (l == LCONV-1) ? pooled : nullptr);
    }

    head_kernel<<<BATCH, 128, 0, stream>>>(pooled, r_x, linr_w, linr_b,
                                           lino_w1, lino_b1, lino_w2, lino_b2, out);
}